// Round 6
// baseline (726.540 us; speedup 1.0000x reference)
//
#include <hip/hip_runtime.h>

// VoxelPooler via bucket sort.
// R5 622us | R6 4-pt float4 gather 600us | R7 ch-sliced gather 716us (REGR:
// 4x gather transactions) | R8 merged-yt+NT 626us | R9 gather-ILP 635us
// (REGR, pool=225us measured: 1.78 TB/s, WRITE=333MB, FETCH=59MB(!),
// VALU 6.7%, conflicts 4% -> write-drain limited) | R10 XCD swizzle 598us
// (swizzle NULL: DRAM page locality is device-wide, not per-XCD).
// R11: TWO-PHASE. Direct writes are inherently 400-B granules at 160-KB
// stride x 1536 concurrent blocks = ~28% DRAM write efficiency. Phase A
// pools into scratch with 25.6-KB CONTIGUOUS per-block writes (page-
// efficient); phase B is a pure permutation: each block writes one 160-KB
// contiguous channel plane, reading scratch (mostly L3-resident) densely
// with the whole 2048-block grid co-resident. ws poison = 1.31 GB => ws
// fits the 334 MB need; runtime-gated with R10-direct and R4 fallbacks.
// geometry [B=4, N=6, D=41, H=16, W=44, 3] f32
// features [B, N, D, H, W, C=64] f32
// out      [B, Z*C=512, X=200, Y=200] f32

#define GRID_X 200
#define GRID_Y 200
#define GRID_Z 8
#define NCH 64
#define NB 4
#define PTS_PER_BATCH (6 * 41 * 16 * 44)   // 173184
#define TOTAL_POINTS (NB * PTS_PER_BATCH)  // 692736
#define OUT_FLOATS ((long long)NB * GRID_Z * NCH * GRID_X * GRID_Y)  // 81,920,000

#define YT 2             // y tiles per x-row
#define TILE_Y 100       // GRID_Y / YT
#define NBUCKET (NB * GRID_Z * GRID_X * YT)   // 12800
#define NXCD 8
#define LDS_STRIDE 65    // acc[y][c] padded
#define TILE_FLOATS (NCH * TILE_Y)            // 6400 floats = 25.6 KB / bucket

// ws layout (ints), then float4-aligned scratch:
// cnt[NBUCKET] | starts[NBUCKET+1] | cursor[NBUCKET] | sorted[TOTAL] | pcode[TOTAL] | scratch[12800*6400 f32]
#define WS_CNT     0
#define WS_STARTS  (NBUCKET)
#define WS_CURSOR  (2 * NBUCKET + 1)
#define WS_SORTED  (3 * NBUCKET + 1)
#define WS_PCODE   (3 * NBUCKET + 1 + TOTAL_POINTS)
#define WS_INTS    (3 * NBUCKET + 1 + 2 * TOTAL_POINTS)
#define WS_SCRATCH ((WS_INTS + 3) & ~3)       // 16-B aligned float region
#define WS_INTS_2PH ((size_t)WS_SCRATCH + (size_t)NBUCKET * TILE_FLOATS)

__device__ __forceinline__ bool point_voxel(const float* __restrict__ geom,
                                            const float* __restrict__ vsz,
                                            const float* __restrict__ vorg,
                                            int i, int& vx, int& vy, int& vz) {
    float px = geom[(size_t)i * 3 + 0];
    float py = geom[(size_t)i * 3 + 1];
    float pz = geom[(size_t)i * 3 + 2];
    // Exact IEEE divide + floorf to match the numpy reference at bin edges.
    vx = (int)floorf((px - vorg[0]) / vsz[0]);
    vy = (int)floorf((py - vorg[1]) / vsz[1]);
    vz = (int)floorf((pz - vorg[2]) / vsz[2]);
    return (vx >= 0 && vx < GRID_X && vy >= 0 && vy < GRID_Y &&
            vz >= 0 && vz < GRID_Z);
}

__global__ __launch_bounds__(256) void zero_cnt_kernel(int* __restrict__ cnt) {
    int i = blockIdx.x * 256 + threadIdx.x;
    if (i < NBUCKET) cnt[i] = 0;
}

// pcode: bit31=valid, bits[20:14]=yl, bits[13:0]=bucket.
__global__ __launch_bounds__(256) void hist_kernel(
    const float* __restrict__ geom, const float* __restrict__ vsz,
    const float* __restrict__ vorg, int* __restrict__ cnt,
    unsigned* __restrict__ pcode) {
    int i = blockIdx.x * 256 + threadIdx.x;
    if (i >= TOTAL_POINTS) return;
    int vx, vy, vz;
    unsigned code = 0;
    if (point_voxel(geom, vsz, vorg, i, vx, vy, vz)) {
        int b = i / PTS_PER_BATCH;
        int yt = vy / TILE_Y;
        int yl = vy - yt * TILE_Y;
        int bucket = ((b * GRID_Z + vz) * GRID_X + vx) * YT + yt;
        code = 0x80000000u | ((unsigned)yl << 14) | (unsigned)bucket;
        atomicAdd(&cnt[bucket], 1);
    }
    pcode[i] = code;
}

// One block, 256 threads, each owns 50 contiguous counters.
__global__ __launch_bounds__(256) void scan_kernel(
    const int* __restrict__ cnt, int* __restrict__ starts, int* __restrict__ cursor) {
    __shared__ int partial[256];
    int t = threadIdx.x;
    const int CHUNK = NBUCKET / 256;   // 50
    int base = t * CHUNK;
    int s = 0;
    for (int j = 0; j < CHUNK; ++j) s += cnt[base + j];
    partial[t] = s;
    __syncthreads();
    for (int off = 1; off < 256; off <<= 1) {
        int v = (t >= off) ? partial[t - off] : 0;
        __syncthreads();
        partial[t] += v;
        __syncthreads();
    }
    int run = partial[t] - s;   // exclusive prefix of this chunk
    for (int j = 0; j < CHUNK; ++j) {
        int c = cnt[base + j];
        starts[base + j] = run;
        cursor[base + j] = run;
        run += c;
    }
    if (t == 255) starts[NBUCKET] = run;
}

__global__ __launch_bounds__(256) void scatter_idx_kernel(
    const unsigned* __restrict__ pcode, int* __restrict__ cursor,
    unsigned* __restrict__ sorted) {
    int i = blockIdx.x * 256 + threadIdx.x;
    if (i >= TOTAL_POINTS) return;
    unsigned code = pcode[i];
    if (!(code & 0x80000000u)) return;
    int bucket = (int)(code & 0x3FFFu);
    unsigned yl = (code >> 14) & 0x7Fu;
    int pos = atomicAdd(&cursor[bucket], 1);
    sorted[pos] = (unsigned)i | (yl << 20);   // i < 2^20, yl < 128
}

// Phase A: one block per bucket. R6 gather (4 pts/wave-iter, 16 lanes x
// float4 = 1 KB/instr, 256-B rows). Epilogue writes the [64c][100y] tile
// CONTIGUOUSLY at scratch4[bid*1600]: 25.6-KB sequential burst per block
// -> DRAM-page-efficient, full L2 lines (vs 64 scattered 400-B segments).
__global__ __launch_bounds__(256) void pool_scratch_kernel(
    const float4* __restrict__ feat4, const unsigned* __restrict__ sorted,
    const int* __restrict__ starts, float4* __restrict__ scratch4) {
    __shared__ __align__(16) float acc[TILE_Y * LDS_STRIDE];   // 26000 B
    int t = threadIdx.x;
    int bid = blockIdx.x;

    float4* a4 = (float4*)acc;
    for (int i = t; i < TILE_Y * LDS_STRIDE / 4; i += 256)
        a4[i] = make_float4(0.f, 0.f, 0.f, 0.f);
    __syncthreads();

    int s0 = starts[bid];
    int s1 = starts[bid + 1];
    int w = t >> 6;            // wave 0..3
    int g = (t >> 4) & 3;      // point slot within wave
    int l = t & 15;            // float4 slot: channels 4l..4l+3

    for (int p0 = s0 + w * 4; p0 < s1; p0 += 16) {
        int p = p0 + g;
        if (p < s1) {
            unsigned pk = sorted[p];
            unsigned idx = pk & 0xFFFFFu;
            unsigned yl = pk >> 20;
            float4 f = feat4[(size_t)idx * 16 + l];
            float* row = &acc[yl * LDS_STRIDE + 4 * l];
            atomicAdd(row + 0, f.x);
            atomicAdd(row + 1, f.y);
            atomicAdd(row + 2, f.z);
            atomicAdd(row + 3, f.w);
        }
    }
    __syncthreads();

    // tile layout [cc][100y]: float4 index i -> cc=i/25, j=i%25 (y0=4j).
    for (int i = t; i < TILE_FLOATS / 4; i += 256) {
        int cc = i / (TILE_Y / 4);
        int j = i % (TILE_Y / 4);
        int y0 = 4 * j;
        float4 v = make_float4(acc[(y0 + 0) * LDS_STRIDE + cc],
                               acc[(y0 + 1) * LDS_STRIDE + cc],
                               acc[(y0 + 2) * LDS_STRIDE + cc],
                               acc[(y0 + 3) * LDS_STRIDE + cc]);
        scratch4[(size_t)bid * (TILE_FLOATS / 4) + i] = v;
    }
}

// Phase B: pure permutation. Block = (bz, cc) plane; writes 160 KB
// CONTIGUOUS. Reads 400 x 400-B chunks (cc's slice of each tile); entire
// 2048-block grid is co-resident (8 blk/CU) so tiles are covered densely
// and mostly served from L3 (scratch just written).
__global__ __launch_bounds__(256) void transpose_kernel(
    const float4* __restrict__ scratch4, float4* __restrict__ out4) {
    int t = threadIdx.x;
    int cc = blockIdx.x & (NCH - 1);
    int bz = blockIdx.x >> 6;          // b*GRID_Z + z, 0..31
    // bucket for (bz, seg) = bz*400 + seg, seg = 2x+yt; out plane offset
    // (floats) x*200 + yt*100 + y = seg*100 + y  -> linear in i.
    const size_t src_base = (size_t)bz * (GRID_X * YT) * (TILE_FLOATS / 4)
                            + (size_t)cc * (TILE_Y / 4);
    const size_t dst_base = ((size_t)bz * NCH + cc) * (GRID_X * GRID_Y / 4);
    for (int i = t; i < GRID_X * GRID_Y / 4; i += 256) {   // 10000 float4
        int seg = i / (TILE_Y / 4);
        int j = i - seg * (TILE_Y / 4);
        out4[dst_base + i] =
            scratch4[src_base + (size_t)seg * (TILE_FLOATS / 4) + j];
    }
}

// ---------- mid-size ws fallback: R10 direct pool ----------
__global__ __launch_bounds__(256) void pool_direct_kernel(
    const float4* __restrict__ feat4, const unsigned* __restrict__ sorted,
    const int* __restrict__ starts, float4* __restrict__ out4) {
    __shared__ __align__(16) float acc[TILE_Y * LDS_STRIDE];
    int t = threadIdx.x;
    int bid = (blockIdx.x % NXCD) * (NBUCKET / NXCD) + blockIdx.x / NXCD;

    float4* a4 = (float4*)acc;
    for (int i = t; i < TILE_Y * LDS_STRIDE / 4; i += 256)
        a4[i] = make_float4(0.f, 0.f, 0.f, 0.f);
    __syncthreads();

    int s0 = starts[bid];
    int s1 = starts[bid + 1];
    int w = t >> 6;
    int g = (t >> 4) & 3;
    int l = t & 15;

    for (int p0 = s0 + w * 4; p0 < s1; p0 += 16) {
        int p = p0 + g;
        if (p < s1) {
            unsigned pk = sorted[p];
            unsigned idx = pk & 0xFFFFFu;
            unsigned yl = pk >> 20;
            float4 f = feat4[(size_t)idx * 16 + l];
            float* row = &acc[yl * LDS_STRIDE + 4 * l];
            atomicAdd(row + 0, f.x);
            atomicAdd(row + 1, f.y);
            atomicAdd(row + 2, f.z);
            atomicAdd(row + 3, f.w);
        }
    }
    __syncthreads();

    int yt = bid & 1;
    int x = (bid >> 1) % GRID_X;
    int bz = (bid >> 1) / GRID_X;

    for (int i = t; i < NCH * (TILE_Y / 4); i += 256) {
        int cc = i / (TILE_Y / 4);
        int j = i % (TILE_Y / 4);
        int y0 = 4 * j;
        float4 v = make_float4(acc[(y0 + 0) * LDS_STRIDE + cc],
                               acc[(y0 + 1) * LDS_STRIDE + cc],
                               acc[(y0 + 2) * LDS_STRIDE + cc],
                               acc[(y0 + 3) * LDS_STRIDE + cc]);
        size_t o4 = (((size_t)bz * NCH + cc) * GRID_X + x) * (GRID_Y / 4)
                    + yt * (TILE_Y / 4) + j;
        out4[o4] = v;
    }
}

// ---------- fallback path (R4): atomic scatter ----------
__global__ __launch_bounds__(256) void zero_out_kernel(float4* __restrict__ out) {
    const long long n4 = OUT_FLOATS / 4;
    long long stride = (long long)gridDim.x * blockDim.x;
    for (long long i = blockIdx.x * (long long)blockDim.x + threadIdx.x;
         i < n4; i += stride)
        out[i] = make_float4(0.f, 0.f, 0.f, 0.f);
}

__global__ __launch_bounds__(256) void voxel_scatter_kernel(
    const float* __restrict__ geom, const float* __restrict__ feat,
    const float* __restrict__ vsz, const float* __restrict__ vorg,
    float* __restrict__ out) {
    int gid = blockIdx.x * blockDim.x + threadIdx.x;
    int pt = gid >> 6;
    int c = gid & 63;
    if (pt >= TOTAL_POINTS) return;
    int vx, vy, vz;
    if (!point_voxel(geom, vsz, vorg, pt, vx, vy, vz)) return;
    int b = pt / PTS_PER_BATCH;
    float f = feat[(size_t)pt * NCH + c];
    size_t idx = ((((size_t)b * GRID_Z + vz) * NCH + c) * GRID_X + vx) * GRID_Y + vy;
    atomicAdd(out + idx, f);
}

extern "C" void kernel_launch(void* const* d_in, const int* in_sizes, int n_in,
                              void* d_out, int out_size, void* d_ws, size_t ws_size,
                              hipStream_t stream) {
    const float* geom = (const float*)d_in[0];
    const float* feat = (const float*)d_in[1];
    const float* vsz  = (const float*)d_in[2];
    const float* vorg = (const float*)d_in[3];
    float* out = (float*)d_out;

    if (ws_size >= (size_t)WS_INTS * sizeof(int)) {
        int* ws = (int*)d_ws;
        int* cnt = ws + WS_CNT;
        int* starts = ws + WS_STARTS;
        int* cursor = ws + WS_CURSOR;
        unsigned* sorted = (unsigned*)(ws + WS_SORTED);
        unsigned* pcode  = (unsigned*)(ws + WS_PCODE);

        zero_cnt_kernel<<<(NBUCKET + 255) / 256, 256, 0, stream>>>(cnt);
        hist_kernel<<<TOTAL_POINTS / 256, 256, 0, stream>>>(geom, vsz, vorg, cnt, pcode);
        scan_kernel<<<1, 256, 0, stream>>>(cnt, starts, cursor);
        scatter_idx_kernel<<<TOTAL_POINTS / 256, 256, 0, stream>>>(pcode, cursor, sorted);

        if (ws_size >= WS_INTS_2PH * sizeof(int) + 16) {
            float4* scratch4 = (float4*)(ws + WS_SCRATCH);
            pool_scratch_kernel<<<NBUCKET, 256, 0, stream>>>(
                (const float4*)feat, sorted, starts, scratch4);
            transpose_kernel<<<NB * GRID_Z * NCH, 256, 0, stream>>>(
                scratch4, (float4*)out);
        } else {
            pool_direct_kernel<<<NBUCKET, 256, 0, stream>>>(
                (const float4*)feat, sorted, starts, (float4*)out);
        }
    } else {
        // ws too small: R4 atomic-scatter fallback
        zero_out_kernel<<<2048, 256, 0, stream>>>((float4*)out);
        const long long total_threads = (long long)TOTAL_POINTS * NCH;
        voxel_scatter_kernel<<<(int)((total_threads + 255) / 256), 256, 0, stream>>>(
            geom, feat, vsz, vorg, out);
    }
}

// Round 7
// 629.052 us; speedup vs baseline: 1.1550x; 1.1550x over previous
//
#include <hip/hip_runtime.h>

// VoxelPooler via bucket sort.
// R5 622 | R6 600 | R7 ch-sliced gather 716 (REGR) | R8 merged-yt+NT 626 |
// R9 gather-ILP 635 (pool measured 225us: 1.78 TB/s, idle pipes) |
// R10 XCD swizzle 598 (null) | R11 two-phase scratch 726 (REGR: scratch+
// features > L3, phase B read cold 400-B granules).
// UNIFIED THEORY (R12): the harness re-poisons ws (1.31 GB fill) before
// every timed call, flushing L3. Pool's gather therefore reads ~117 MB of
// COLD random 256-B feature rows from HBM each iteration (rocprof's
// FETCH=59MB was a replay-warm-L3 artifact), mixed with the 333-MB write
// stream -> ~2 TB/s DRAM efficiency. Explains R7 (64-B random reads 4x
// worse), write-trick nulls, occupancy sensitivity.
// R12 = R10 + (a) sequential 177-MB feature PREFETCH kernel right before
// pool (repopulates memory-side L3 at streaming rate), (b) nontemporal
// output stores (evict-first: don't let the write stream evict features).
// geometry [B=4, N=6, D=41, H=16, W=44, 3] f32
// features [B, N, D, H, W, C=64] f32
// out      [B, Z*C=512, X=200, Y=200] f32

#define GRID_X 200
#define GRID_Y 200
#define GRID_Z 8
#define NCH 64
#define NB 4
#define PTS_PER_BATCH (6 * 41 * 16 * 44)   // 173184
#define TOTAL_POINTS (NB * PTS_PER_BATCH)  // 692736
#define OUT_FLOATS ((long long)NB * GRID_Z * NCH * GRID_X * GRID_Y)  // 81,920,000

#define YT 2             // y tiles per x-row
#define TILE_Y 100       // GRID_Y / YT
#define NBUCKET (NB * GRID_Z * GRID_X * YT)   // 12800
#define NXCD 8
#define LDS_STRIDE 65    // acc[y][c] padded: gather 2-way banks, epilogue ok

typedef float nt4 __attribute__((ext_vector_type(4)));   // native vec for nt-store

// ws layout (ints):
// cnt[NBUCKET] | starts[NBUCKET+1] | cursor[NBUCKET] | sorted[TOTAL_POINTS] | pcode[TOTAL_POINTS]
#define WS_CNT     0
#define WS_STARTS  (NBUCKET)
#define WS_CURSOR  (2 * NBUCKET + 1)
#define WS_SORTED  (3 * NBUCKET + 1)
#define WS_PCODE   (3 * NBUCKET + 1 + TOTAL_POINTS)
#define WS_INTS    (3 * NBUCKET + 1 + 2 * TOTAL_POINTS)

__device__ __forceinline__ bool point_voxel(const float* __restrict__ geom,
                                            const float* __restrict__ vsz,
                                            const float* __restrict__ vorg,
                                            int i, int& vx, int& vy, int& vz) {
    float px = geom[(size_t)i * 3 + 0];
    float py = geom[(size_t)i * 3 + 1];
    float pz = geom[(size_t)i * 3 + 2];
    // Exact IEEE divide + floorf to match the numpy reference at bin edges.
    vx = (int)floorf((px - vorg[0]) / vsz[0]);
    vy = (int)floorf((py - vorg[1]) / vsz[1]);
    vz = (int)floorf((pz - vorg[2]) / vsz[2]);
    return (vx >= 0 && vx < GRID_X && vy >= 0 && vy < GRID_Y &&
            vz >= 0 && vz < GRID_Z);
}

__global__ __launch_bounds__(256) void zero_cnt_kernel(int* __restrict__ cnt) {
    int i = blockIdx.x * 256 + threadIdx.x;
    if (i < NBUCKET) cnt[i] = 0;
}

// Histogram + cache packed (bucket, y_local) per point so scatter_idx skips
// the geometry re-read. pcode: bit31=valid, bits[20:14]=yl, bits[13:0]=bucket.
__global__ __launch_bounds__(256) void hist_kernel(
    const float* __restrict__ geom, const float* __restrict__ vsz,
    const float* __restrict__ vorg, int* __restrict__ cnt,
    unsigned* __restrict__ pcode) {
    int i = blockIdx.x * 256 + threadIdx.x;
    if (i >= TOTAL_POINTS) return;
    int vx, vy, vz;
    unsigned code = 0;
    if (point_voxel(geom, vsz, vorg, i, vx, vy, vz)) {
        int b = i / PTS_PER_BATCH;
        int yt = vy / TILE_Y;
        int yl = vy - yt * TILE_Y;
        int bucket = ((b * GRID_Z + vz) * GRID_X + vx) * YT + yt;
        code = 0x80000000u | ((unsigned)yl << 14) | (unsigned)bucket;
        atomicAdd(&cnt[bucket], 1);
    }
    pcode[i] = code;
}

// One block, 256 threads, each owns 50 contiguous counters.
__global__ __launch_bounds__(256) void scan_kernel(
    const int* __restrict__ cnt, int* __restrict__ starts, int* __restrict__ cursor) {
    __shared__ int partial[256];
    int t = threadIdx.x;
    const int CHUNK = NBUCKET / 256;   // 50
    int base = t * CHUNK;
    int s = 0;
    for (int j = 0; j < CHUNK; ++j) s += cnt[base + j];
    partial[t] = s;
    __syncthreads();
    for (int off = 1; off < 256; off <<= 1) {
        int v = (t >= off) ? partial[t - off] : 0;
        __syncthreads();
        partial[t] += v;
        __syncthreads();
    }
    int run = partial[t] - s;   // exclusive prefix of this chunk
    for (int j = 0; j < CHUNK; ++j) {
        int c = cnt[base + j];
        starts[base + j] = run;
        cursor[base + j] = run;
        run += c;
    }
    if (t == 255) starts[NBUCKET] = run;
}

__global__ __launch_bounds__(256) void scatter_idx_kernel(
    const unsigned* __restrict__ pcode, int* __restrict__ cursor,
    unsigned* __restrict__ sorted) {
    int i = blockIdx.x * 256 + threadIdx.x;
    if (i >= TOTAL_POINTS) return;
    unsigned code = pcode[i];
    if (!(code & 0x80000000u)) return;
    int bucket = (int)(code & 0x3FFFu);
    unsigned yl = (code >> 14) & 0x7Fu;
    int pos = atomicAdd(&cursor[bucket], 1);
    sorted[pos] = (unsigned)i | (yl << 20);   // i < 2^20, yl < 128
}

// Sequential streaming read of the whole feature tensor: repopulates the
// memory-side L3 (flushed by the harness's 1.31-GB ws poison fill) at the
// 6.3 TB/s streaming rate, so pool's random 256-B gathers become L3 hits.
// asm sink keeps the loads live (no stores, no DCE — guide rule #17).
__global__ __launch_bounds__(256) void prefetch_kernel(
    const float4* __restrict__ feat4) {
    const size_t n4 = (size_t)TOTAL_POINTS * (NCH / 4);   // 11,083,776 float4
    size_t stride = (size_t)gridDim.x * 256;
    for (size_t i = (size_t)blockIdx.x * 256 + threadIdx.x; i < n4; i += stride) {
        float4 v = feat4[i];
        asm volatile("" :: "v"(v.x), "v"(v.y), "v"(v.z), "v"(v.w));
    }
}

// One block per bucket (b, z, x, yt). Gather: 4 points per wave-iteration,
// 16 lanes x float4 each (1 KB / wave load instr). Accumulate acc[y][c]
// in LDS, dense float4 write-out — NONTEMPORAL (evict-first) so the
// 333-MB write stream doesn't evict the prefetched features from L3.
__global__ __launch_bounds__(256) void pool_kernel(
    const float4* __restrict__ feat4, const unsigned* __restrict__ sorted,
    const int* __restrict__ starts, float* __restrict__ out) {
    __shared__ __align__(16) float acc[TILE_Y * LDS_STRIDE];   // 26000 B
    int t = threadIdx.x;
    // bijective chunked swizzle (NBUCKET % NXCD == 0); measured null but
    // harmless — keep L2-local gather/sorted reads.
    int bid = (blockIdx.x % NXCD) * (NBUCKET / NXCD) + blockIdx.x / NXCD;

    // zero LDS with float4 stores: 6500 floats = 1625 float4
    float4* a4 = (float4*)acc;
    for (int i = t; i < TILE_Y * LDS_STRIDE / 4; i += 256)
        a4[i] = make_float4(0.f, 0.f, 0.f, 0.f);
    __syncthreads();

    int s0 = starts[bid];
    int s1 = starts[bid + 1];
    int w = t >> 6;            // wave 0..3
    int g = (t >> 4) & 3;      // point slot within wave
    int l = t & 15;            // float4 slot: channels 4l..4l+3

    for (int p0 = s0 + w * 4; p0 < s1; p0 += 16) {
        int p = p0 + g;
        if (p < s1) {
            unsigned pk = sorted[p];
            unsigned idx = pk & 0xFFFFFu;
            unsigned yl = pk >> 20;
            float4 f = feat4[(size_t)idx * 16 + l];
            float* row = &acc[yl * LDS_STRIDE + 4 * l];
            atomicAdd(row + 0, f.x);
            atomicAdd(row + 1, f.y);
            atomicAdd(row + 2, f.z);
            atomicAdd(row + 3, f.w);
        }
    }
    __syncthreads();

    // bid = ((b*GZ+z)*GX + x)*YT + yt
    int yt = bid & 1;
    int x = (bid >> 1) % GRID_X;
    int bz = (bid >> 1) / GRID_X;   // b*GRID_Z + z

    // 64 channels x 25 float4 (=100 y) = 1600 float4 stores, coalesced,
    // nontemporal (evict-first).
    nt4* out4 = (nt4*)out;
    for (int i = t; i < NCH * (TILE_Y / 4); i += 256) {
        int cc = i / (TILE_Y / 4);
        int j = i % (TILE_Y / 4);
        int y0 = 4 * j;
        nt4 v = {acc[(y0 + 0) * LDS_STRIDE + cc],
                 acc[(y0 + 1) * LDS_STRIDE + cc],
                 acc[(y0 + 2) * LDS_STRIDE + cc],
                 acc[(y0 + 3) * LDS_STRIDE + cc]};
        // float index: (((bz*64+cc)*200 + x)*200 + yt*100 + 4j), /4 below
        size_t o4 = (((size_t)bz * NCH + cc) * GRID_X + x) * (GRID_Y / 4)
                    + yt * (TILE_Y / 4) + j;
        __builtin_nontemporal_store(v, &out4[o4]);
    }
}

// ---------- fallback path (R4): atomic scatter ----------
__global__ __launch_bounds__(256) void zero_out_kernel(float4* __restrict__ out) {
    const long long n4 = OUT_FLOATS / 4;
    long long stride = (long long)gridDim.x * blockDim.x;
    for (long long i = blockIdx.x * (long long)blockDim.x + threadIdx.x;
         i < n4; i += stride)
        out[i] = make_float4(0.f, 0.f, 0.f, 0.f);
}

__global__ __launch_bounds__(256) void voxel_scatter_kernel(
    const float* __restrict__ geom, const float* __restrict__ feat,
    const float* __restrict__ vsz, const float* __restrict__ vorg,
    float* __restrict__ out) {
    int gid = blockIdx.x * blockDim.x + threadIdx.x;
    int pt = gid >> 6;
    int c = gid & 63;
    if (pt >= TOTAL_POINTS) return;
    int vx, vy, vz;
    if (!point_voxel(geom, vsz, vorg, pt, vx, vy, vz)) return;
    int b = pt / PTS_PER_BATCH;
    float f = feat[(size_t)pt * NCH + c];
    size_t idx = ((((size_t)b * GRID_Z + vz) * NCH + c) * GRID_X + vx) * GRID_Y + vy;
    atomicAdd(out + idx, f);
}

extern "C" void kernel_launch(void* const* d_in, const int* in_sizes, int n_in,
                              void* d_out, int out_size, void* d_ws, size_t ws_size,
                              hipStream_t stream) {
    const float* geom = (const float*)d_in[0];
    const float* feat = (const float*)d_in[1];
    const float* vsz  = (const float*)d_in[2];
    const float* vorg = (const float*)d_in[3];
    float* out = (float*)d_out;

    if (ws_size >= (size_t)WS_INTS * sizeof(int)) {
        int* ws = (int*)d_ws;
        int* cnt = ws + WS_CNT;
        int* starts = ws + WS_STARTS;
        int* cursor = ws + WS_CURSOR;
        unsigned* sorted = (unsigned*)(ws + WS_SORTED);
        unsigned* pcode  = (unsigned*)(ws + WS_PCODE);

        zero_cnt_kernel<<<(NBUCKET + 255) / 256, 256, 0, stream>>>(cnt);
        hist_kernel<<<TOTAL_POINTS / 256, 256, 0, stream>>>(geom, vsz, vorg, cnt, pcode);
        scan_kernel<<<1, 256, 0, stream>>>(cnt, starts, cursor);
        scatter_idx_kernel<<<TOTAL_POINTS / 256, 256, 0, stream>>>(pcode, cursor, sorted);
        prefetch_kernel<<<2048, 256, 0, stream>>>((const float4*)feat);
        pool_kernel<<<NBUCKET, 256, 0, stream>>>(
            (const float4*)feat, sorted, starts, (float*)out);
    } else {
        // ws too small: R4 atomic-scatter fallback
        zero_out_kernel<<<2048, 256, 0, stream>>>((float4*)out);
        const long long total_threads = (long long)TOTAL_POINTS * NCH;
        voxel_scatter_kernel<<<(int)((total_threads + 255) / 256), 256, 0, stream>>>(
            geom, feat, vsz, vorg, out);
    }
}

// Round 8
// 626.160 us; speedup vs baseline: 1.1603x; 1.0046x over previous
//
#include <hip/hip_runtime.h>

// VoxelPooler via bucket sort.
// R5 622 | R6 600 | R7 ch-sliced 716 REGR | R8 merged-yt+NT 626 |
// R9 guard-ILP 635 REGR (pool 225us: 1.78 TB/s, all pipes idle) |
// R10 XCD swizzle 598 (null) | R11 two-phase 726 REGR (cold scratch) |
// R12 L3-prefetch+NT 629 (+31 = prefetch cost; cold-read theory DEAD).
// Falsified so far: write-granule, XCD locality, scratch two-phase,
// cold-L3 reads, guard-style ILP. Remaining candidate (R13): the gather's
// DEPENDENT-LOAD CHAIN — sorted[p] (global) -> feat[idx] (global) serializes
// 2 latencies x ~4 iters per wave. Fix: stage the bucket's sorted slice in
// LDS once (1 coalesced load), then 2-deep software-pipeline the feat
// loads (issue next before consuming current; counted vmcnt). Tail via
// clamp+scale-by-0 (atomicAdd(0) harmless) — NO divergent guards (R9's
// mistake). CHUNK=192 keeps LDS 26.8KB -> 6 blocks/CU.
// geometry [B=4, N=6, D=41, H=16, W=44, 3] f32
// features [B, N, D, H, W, C=64] f32
// out      [B, Z*C=512, X=200, Y=200] f32

#define GRID_X 200
#define GRID_Y 200
#define GRID_Z 8
#define NCH 64
#define NB 4
#define PTS_PER_BATCH (6 * 41 * 16 * 44)   // 173184
#define TOTAL_POINTS (NB * PTS_PER_BATCH)  // 692736
#define OUT_FLOATS ((long long)NB * GRID_Z * NCH * GRID_X * GRID_Y)  // 81,920,000

#define YT 2             // y tiles per x-row
#define TILE_Y 100       // GRID_Y / YT
#define NBUCKET (NB * GRID_Z * GRID_X * YT)   // 12800
#define NXCD 8
#define LDS_STRIDE 65    // acc[y][c] padded: gather 2-way banks, epilogue ok
#define CHUNK_P 192      // sorted-slice staging chunk (26000+768 floats = 26.8KB, 6 blk/CU)

// ws layout (ints):
// cnt[NBUCKET] | starts[NBUCKET+1] | cursor[NBUCKET] | sorted[TOTAL_POINTS] | pcode[TOTAL_POINTS]
#define WS_CNT     0
#define WS_STARTS  (NBUCKET)
#define WS_CURSOR  (2 * NBUCKET + 1)
#define WS_SORTED  (3 * NBUCKET + 1)
#define WS_PCODE   (3 * NBUCKET + 1 + TOTAL_POINTS)
#define WS_INTS    (3 * NBUCKET + 1 + 2 * TOTAL_POINTS)

__device__ __forceinline__ bool point_voxel(const float* __restrict__ geom,
                                            const float* __restrict__ vsz,
                                            const float* __restrict__ vorg,
                                            int i, int& vx, int& vy, int& vz) {
    float px = geom[(size_t)i * 3 + 0];
    float py = geom[(size_t)i * 3 + 1];
    float pz = geom[(size_t)i * 3 + 2];
    // Exact IEEE divide + floorf to match the numpy reference at bin edges.
    vx = (int)floorf((px - vorg[0]) / vsz[0]);
    vy = (int)floorf((py - vorg[1]) / vsz[1]);
    vz = (int)floorf((pz - vorg[2]) / vsz[2]);
    return (vx >= 0 && vx < GRID_X && vy >= 0 && vy < GRID_Y &&
            vz >= 0 && vz < GRID_Z);
}

__global__ __launch_bounds__(256) void zero_cnt_kernel(int* __restrict__ cnt) {
    int i = blockIdx.x * 256 + threadIdx.x;
    if (i < NBUCKET) cnt[i] = 0;
}

// Histogram + cache packed (bucket, y_local) per point so scatter_idx skips
// the geometry re-read. pcode: bit31=valid, bits[20:14]=yl, bits[13:0]=bucket.
__global__ __launch_bounds__(256) void hist_kernel(
    const float* __restrict__ geom, const float* __restrict__ vsz,
    const float* __restrict__ vorg, int* __restrict__ cnt,
    unsigned* __restrict__ pcode) {
    int i = blockIdx.x * 256 + threadIdx.x;
    if (i >= TOTAL_POINTS) return;
    int vx, vy, vz;
    unsigned code = 0;
    if (point_voxel(geom, vsz, vorg, i, vx, vy, vz)) {
        int b = i / PTS_PER_BATCH;
        int yt = vy / TILE_Y;
        int yl = vy - yt * TILE_Y;
        int bucket = ((b * GRID_Z + vz) * GRID_X + vx) * YT + yt;
        code = 0x80000000u | ((unsigned)yl << 14) | (unsigned)bucket;
        atomicAdd(&cnt[bucket], 1);
    }
    pcode[i] = code;
}

// One block, 256 threads, each owns 50 contiguous counters.
__global__ __launch_bounds__(256) void scan_kernel(
    const int* __restrict__ cnt, int* __restrict__ starts, int* __restrict__ cursor) {
    __shared__ int partial[256];
    int t = threadIdx.x;
    const int CHUNK = NBUCKET / 256;   // 50
    int base = t * CHUNK;
    int s = 0;
    for (int j = 0; j < CHUNK; ++j) s += cnt[base + j];
    partial[t] = s;
    __syncthreads();
    for (int off = 1; off < 256; off <<= 1) {
        int v = (t >= off) ? partial[t - off] : 0;
        __syncthreads();
        partial[t] += v;
        __syncthreads();
    }
    int run = partial[t] - s;   // exclusive prefix of this chunk
    for (int j = 0; j < CHUNK; ++j) {
        int c = cnt[base + j];
        starts[base + j] = run;
        cursor[base + j] = run;
        run += c;
    }
    if (t == 255) starts[NBUCKET] = run;
}

__global__ __launch_bounds__(256) void scatter_idx_kernel(
    const unsigned* __restrict__ pcode, int* __restrict__ cursor,
    unsigned* __restrict__ sorted) {
    int i = blockIdx.x * 256 + threadIdx.x;
    if (i >= TOTAL_POINTS) return;
    unsigned code = pcode[i];
    if (!(code & 0x80000000u)) return;
    int bucket = (int)(code & 0x3FFFu);
    unsigned yl = (code >> 14) & 0x7Fu;
    int pos = atomicAdd(&cursor[bucket], 1);
    sorted[pos] = (unsigned)i | (yl << 20);   // i < 2^20, yl < 128
}

// One block per bucket (b, z, x, yt). Sorted slice staged in LDS (kills the
// sorted->feat dependent-load chain); gather = 4 pts/wave-iter, 16 lanes x
// float4, 2-deep software pipeline (issue next feat load before consuming
// current; compiler emits counted vmcnt(1)). Tail: clamp index, scale 0.
__global__ __launch_bounds__(256) void pool_kernel(
    const float4* __restrict__ feat4, const unsigned* __restrict__ sorted,
    const int* __restrict__ starts, float4* __restrict__ out4) {
    __shared__ __align__(16) float acc[TILE_Y * LDS_STRIDE];   // 26000 B
    __shared__ unsigned spk[CHUNK_P];                          // 768 B
    int t = threadIdx.x;
    // bijective chunked swizzle (NBUCKET % NXCD == 0); measured null but
    // harmless — keeps gather/sorted reads XCD-local.
    int bid = (blockIdx.x % NXCD) * (NBUCKET / NXCD) + blockIdx.x / NXCD;

    // zero LDS with float4 stores: 6500 floats = 1625 float4
    float4* a4 = (float4*)acc;
    for (int i = t; i < TILE_Y * LDS_STRIDE / 4; i += 256)
        a4[i] = make_float4(0.f, 0.f, 0.f, 0.f);
    __syncthreads();

    int s0 = starts[bid];
    int s1 = starts[bid + 1];
    int w = t >> 6;            // wave 0..3
    int g = (t >> 4) & 3;      // point slot within wave
    int l = t & 15;            // float4 slot: channels 4l..4l+3
    int base = 4 * w + g;      // this lane's first point within a chunk

    for (int c0 = s0; c0 < s1; c0 += CHUNK_P) {
        int m = s1 - c0;
        if (m > CHUNK_P) m = CHUNK_P;
        if (t < m) spk[t] = sorted[c0 + t];
        __syncthreads();

        int niter = (m + 15) >> 4;   // block-uniform trip count
        // prologue: stage point A
        int pA = base < m ? base : m - 1;
        float scA = base < m ? 1.0f : 0.0f;
        unsigned pkA = spk[pA];
        float4 fA = feat4[(size_t)(pkA & 0xFFFFFu) * 16 + l];
        for (int j = 1; j < niter; ++j) {
            int idx = base + 16 * j;
            int pB = idx < m ? idx : m - 1;
            float scB = idx < m ? 1.0f : 0.0f;
            unsigned pkB = spk[pB];
            float4 fB = feat4[(size_t)(pkB & 0xFFFFFu) * 16 + l];  // in flight
            float* row = &acc[(pkA >> 20) * LDS_STRIDE + 4 * l];
            atomicAdd(row + 0, scA * fA.x);
            atomicAdd(row + 1, scA * fA.y);
            atomicAdd(row + 2, scA * fA.z);
            atomicAdd(row + 3, scA * fA.w);
            pkA = pkB; fA = fB; scA = scB;
        }
        float* row = &acc[(pkA >> 20) * LDS_STRIDE + 4 * l];
        atomicAdd(row + 0, scA * fA.x);
        atomicAdd(row + 1, scA * fA.y);
        atomicAdd(row + 2, scA * fA.z);
        atomicAdd(row + 3, scA * fA.w);
        __syncthreads();   // protect spk before next chunk's staging
    }
    __syncthreads();

    // bid = ((b*GZ+z)*GX + x)*YT + yt
    int yt = bid & 1;
    int x = (bid >> 1) % GRID_X;
    int bz = (bid >> 1) / GRID_X;   // b*GRID_Z + z

    // 64 channels x 25 float4 (=100 y) = 1600 float4 stores, coalesced.
    for (int i = t; i < NCH * (TILE_Y / 4); i += 256) {
        int cc = i / (TILE_Y / 4);
        int j = i % (TILE_Y / 4);
        int y0 = 4 * j;
        float4 v = make_float4(acc[(y0 + 0) * LDS_STRIDE + cc],
                               acc[(y0 + 1) * LDS_STRIDE + cc],
                               acc[(y0 + 2) * LDS_STRIDE + cc],
                               acc[(y0 + 3) * LDS_STRIDE + cc]);
        // float index: (((bz*64+cc)*200 + x)*200 + yt*100 + 4j), /4 below
        size_t o4 = (((size_t)bz * NCH + cc) * GRID_X + x) * (GRID_Y / 4)
                    + yt * (TILE_Y / 4) + j;
        out4[o4] = v;
    }
}

// ---------- fallback path (R4): atomic scatter ----------
__global__ __launch_bounds__(256) void zero_out_kernel(float4* __restrict__ out) {
    const long long n4 = OUT_FLOATS / 4;
    long long stride = (long long)gridDim.x * blockDim.x;
    for (long long i = blockIdx.x * (long long)blockDim.x + threadIdx.x;
         i < n4; i += stride)
        out[i] = make_float4(0.f, 0.f, 0.f, 0.f);
}

__global__ __launch_bounds__(256) void voxel_scatter_kernel(
    const float* __restrict__ geom, const float* __restrict__ feat,
    const float* __restrict__ vsz, const float* __restrict__ vorg,
    float* __restrict__ out) {
    int gid = blockIdx.x * blockDim.x + threadIdx.x;
    int pt = gid >> 6;
    int c = gid & 63;
    if (pt >= TOTAL_POINTS) return;
    int vx, vy, vz;
    if (!point_voxel(geom, vsz, vorg, pt, vx, vy, vz)) return;
    int b = pt / PTS_PER_BATCH;
    float f = feat[(size_t)pt * NCH + c];
    size_t idx = ((((size_t)b * GRID_Z + vz) * NCH + c) * GRID_X + vx) * GRID_Y + vy;
    atomicAdd(out + idx, f);
}

extern "C" void kernel_launch(void* const* d_in, const int* in_sizes, int n_in,
                              void* d_out, int out_size, void* d_ws, size_t ws_size,
                              hipStream_t stream) {
    const float* geom = (const float*)d_in[0];
    const float* feat = (const float*)d_in[1];
    const float* vsz  = (const float*)d_in[2];
    const float* vorg = (const float*)d_in[3];
    float* out = (float*)d_out;

    if (ws_size >= (size_t)WS_INTS * sizeof(int)) {
        int* ws = (int*)d_ws;
        int* cnt = ws + WS_CNT;
        int* starts = ws + WS_STARTS;
        int* cursor = ws + WS_CURSOR;
        unsigned* sorted = (unsigned*)(ws + WS_SORTED);
        unsigned* pcode  = (unsigned*)(ws + WS_PCODE);

        zero_cnt_kernel<<<(NBUCKET + 255) / 256, 256, 0, stream>>>(cnt);
        hist_kernel<<<TOTAL_POINTS / 256, 256, 0, stream>>>(geom, vsz, vorg, cnt, pcode);
        scan_kernel<<<1, 256, 0, stream>>>(cnt, starts, cursor);
        scatter_idx_kernel<<<TOTAL_POINTS / 256, 256, 0, stream>>>(pcode, cursor, sorted);
        pool_kernel<<<NBUCKET, 256, 0, stream>>>(
            (const float4*)feat, sorted, starts, (float4*)out);
    } else {
        // ws too small: R4 atomic-scatter fallback
        zero_out_kernel<<<2048, 256, 0, stream>>>((float4*)out);
        const long long total_threads = (long long)TOTAL_POINTS * NCH;
        voxel_scatter_kernel<<<(int)((total_threads + 255) / 256), 256, 0, stream>>>(
            geom, feat, vsz, vorg, out);
    }
}